// Round 6
// baseline (1139.447 us; speedup 1.0000x reference)
//
#include <hip/hip_runtime.h>
#include <hip/hip_fp16.h>

// DEQ classifier, dx-packed MFMA version.
// One block per image (1024 x 512 threads, 8 waves). LDS: two planes of
// 8-channel f16 pixel bundles (16 B) on a 36x36 zero-padded grid, with
// bundle-address swizzle  bofs(y,x) = ((y*36+x)*16) ^ ((x&8)<<1)
// applied by ALL readers/writers (kills 4-way bank conflicts on the
// stride-2 anchor reads).
//   zxb: [z0..z4, img0..2]    hbb: [h0..h5, 0, 0]
// Conv as MFMA 16x16x32 with operands:
//   A[16 rows=(dx*8+oc)][32 k] : weights, prepacked in d_ws (kx = tx-dx)
//   B[32 k][16 cols=anchor a]  : pixel bundle at (ay+ty, 2a+tx), 1 b128/lane
//   k = (tap = ty*6+tx over 5x6 window, ch); 8 chunks of 4 taps.
//   D: col=lane&15=anchor, row=(lane>>4)*4+reg = dx*8+oc
//      -> lane (a, tg): dx = tg>>1, ch-half = tg&1; one b64 write per row.
// GroupNorm folded into conv2 (B2' = B2*sc, h-pads = -sh/sc, bias2' fold).

typedef _Float16 half8 __attribute__((ext_vector_type(8)));
typedef float f32x4 __attribute__((ext_vector_type(4)));

__device__ __forceinline__ unsigned pk2(float a, float b) {
    __half2 h = __float22half2_rn(make_float2(a, b));
    return *reinterpret_cast<unsigned*>(&h);
}
__device__ __forceinline__ float2 up2(unsigned u) {
    __half2 h = *reinterpret_cast<__half2*>(&u);
    return __half22float2(h);
}
__device__ __forceinline__ unsigned hmul2(unsigned a, unsigned b) {
    __half2 r = __hmul2(*reinterpret_cast<__half2*>(&a), *reinterpret_cast<__half2*>(&b));
    return *reinterpret_cast<unsigned*>(&r);
}
__device__ __forceinline__ float lrelu(float x) { return fmaxf(x, 0.01f * x); }
__device__ __forceinline__ int bofs(int y, int x) {
    return ((y * 36 + x) * 16) ^ ((x & 8) << 1);
}

// ---- prep: dx-packed A-fragments + tap-sum table ----
// ws[0..2047]    : conv1 A-frags, 8 chunks x 64 lanes x 4 dw
//   lane l: row = l&15 (dx=row>>3, oc=row&7), tap = 4c + (l>>4); elem j = ch j
//   value = w1[oc][ch][ty][tx-dx] (ty=tap/6, tx=tap%6), 0 if OOB/oc>=6/tap>=30
// ws[2048..4095] : conv2 A-frags from w2 (0 if oc>=5, ch>=6)
// ws[4096..4125] : S2[oc][ch] = sum_tap w2[oc][ch][tap]  (f32)
__global__ void pack_weights(const float* __restrict__ w1,
                             const float* __restrict__ w2,
                             unsigned* __restrict__ ws)
{
    int t = blockIdx.x * 256 + threadIdx.x;
    if (t < 512) {
        int c = t >> 6, l = t & 63;
        int row = l & 15, tgw = l >> 4;
        int dx = row >> 3, oc = row & 7, tap = 4 * c + tgw;
        unsigned q[4];
        #pragma unroll
        for (int d = 0; d < 4; ++d) {
            float v0 = 0.f, v1 = 0.f;
            if (oc < 6 && tap < 30) {
                int ty = tap / 6, kx = tap % 6 - dx;
                if (kx >= 0 && kx < 5) {
                    v0 = w1[(oc * 8 + 2 * d) * 25 + ty * 5 + kx];
                    v1 = w1[(oc * 8 + 2 * d + 1) * 25 + ty * 5 + kx];
                }
            }
            q[d] = pk2(v0, v1);
        }
        *(uint4*)&ws[t * 4] = make_uint4(q[0], q[1], q[2], q[3]);
    } else if (t < 1024) {
        int u = t - 512;
        int c = u >> 6, l = u & 63;
        int row = l & 15, tgw = l >> 4;
        int dx = row >> 3, oc = row & 7, tap = 4 * c + tgw;
        unsigned q[4];
        #pragma unroll
        for (int d = 0; d < 4; ++d) {
            float v0 = 0.f, v1 = 0.f;
            if (oc < 5 && tap < 30) {
                int ty = tap / 6, kx = tap % 6 - dx;
                if (kx >= 0 && kx < 5) {
                    if (2 * d < 6)     v0 = w2[(oc * 6 + 2 * d) * 25 + ty * 5 + kx];
                    if (2 * d + 1 < 6) v1 = w2[(oc * 6 + 2 * d + 1) * 25 + ty * 5 + kx];
                }
            }
            q[d] = pk2(v0, v1);
        }
        *(uint4*)&ws[2048 + u * 4] = make_uint4(q[0], q[1], q[2], q[3]);
    } else if (t < 1054) {
        int idx = t - 1024;
        int oc = idx / 6, ch = idx % 6;
        float s = 0.f;
        for (int tap = 0; tap < 25; ++tap) s += w2[(oc * 6 + ch) * 25 + tap];
        ((float*)ws)[4096 + idx] = s;
    }
}

__global__ __launch_bounds__(512, 6)
void deq_kernel(const float* __restrict__ image,
                const unsigned* __restrict__ wks,
                const float* __restrict__ b1,
                const float* __restrict__ gam, const float* __restrict__ bet,
                const float* __restrict__ b2,
                const float* __restrict__ wh, const float* __restrict__ bh,
                float* __restrict__ out)
{
    __shared__ __align__(16) unsigned zxb[36 * 36 * 4];
    __shared__ __align__(16) unsigned hbb[36 * 36 * 4];
    __shared__ float red[64];
    __shared__ float s2s[32];

    const int n    = blockIdx.x;
    const int tid  = threadIdx.x;
    const int lane = tid & 63;
    const int wid  = tid >> 6;          // 0..7
    const int col  = lane & 15;         // anchor: pixels 2col, 2col+1
    const int tg   = lane >> 4;
    const int dxl  = tg >> 1;           // this lane's output dx
    const int sub  = tg & 1;            // 0: ch0-3 (dw0,1), 1: ch4-7 (dw2,3)

    for (int p = tid; p < 36 * 36 * 4; p += 512) { zxb[p] = 0u; hbb[p] = 0u; }
    if (tid < 30) s2s[tid] = ((const float*)wks)[4096 + tid];
    __syncthreads();

    if (tid < 256) {    // image -> bundle ch 5..7
        const int yy = tid >> 3, xx0 = (tid & 7) << 2;
        float4 i0 = *(const float4*)&image[(n * 3 + 0) * 1024 + yy * 32 + xx0];
        float4 i1 = *(const float4*)&image[(n * 3 + 1) * 1024 + yy * 32 + xx0];
        float4 i2 = *(const float4*)&image[(n * 3 + 2) * 1024 + yy * 32 + xx0];
        float a0[4] = {i0.x, i0.y, i0.z, i0.w};
        float a1[4] = {i1.x, i1.y, i1.z, i1.w};
        float a2[4] = {i2.x, i2.y, i2.z, i2.w};
        #pragma unroll
        for (int i = 0; i < 4; ++i) {
            unsigned* bp = (unsigned*)((char*)zxb + bofs(yy + 2, xx0 + 2 + i));
            bp[2] = pk2(0.f, a0[i]);
            bp[3] = pk2(a1[i], a2[i]);
        }
    }

    // weight A-fragments
    uint4 cw1[8], cw2[8];
    #pragma unroll
    for (int c = 0; c < 8; ++c) {
        cw1[c] = *(const uint4*)&wks[(c * 64 + lane) * 4];
        cw2[c] = *(const uint4*)&wks[2048 + (c * 64 + lane) * 4];
    }
    // per-lane per-chunk B-read byte offsets (tap of this lane-group, swizzled)
    int toff[8];
    #pragma unroll
    for (int c = 0; c < 8; ++c) {
        int t = 4 * c + tg;
        int ty = 0, tx = 0;
        if (t < 30) { ty = t / 6; tx = t % 6; }
        int xr = 2 * col + tx;
        toff[c] = ty * 576 + ((xr * 16) ^ ((xr & 8) << 1));
    }

    float gv[6], bv[6];
    #pragma unroll
    for (int c = 0; c < 6; ++c) { gv[c] = gam[c]; bv[c] = bet[c]; }
    float b1q[4], b2q[4], s2q[24];
    #pragma unroll
    for (int r = 0; r < 4; ++r) {
        int oc = (tg * 4 + r) & 7;
        b1q[r] = (oc < 6) ? b1[oc] : 0.f;
        b2q[r] = (oc < 5) ? b2[oc] : 0.f;
        #pragma unroll
        for (int ch = 0; ch < 6; ++ch)
            s2q[r * 6 + ch] = (oc < 5) ? s2s[oc * 6 + ch] : 0.f;
    }
    const f32x4 ai1 = {b1q[0], b1q[1], b1q[2], b1q[3]};

    __syncthreads();

    const char* zb = (const char*)zxb;
    const char* hb = (const char*)hbb;

    #pragma unroll 1
    for (int it = 0; it < 30; ++it) {
        // ================= conv1 (bias in acc-init) =================
        float ps_lo = 0.f, ps_hi = 0.f, pq_lo = 0.f, pq_hi = 0.f;
        for (int g8 = 0; g8 < 4; ++g8) {
            const int ay = (wid << 2) + g8;
            const int ab = ay * 576;
            f32x4 acc = ai1;
            #pragma unroll
            for (int c = 0; c < 8; ++c) {
                half8 pv = *(const half8*)(zb + ab + toff[c]);
                acc = __builtin_amdgcn_mfma_f32_16x16x32_f16(
                        __builtin_bit_cast(half8, cw1[c]), pv, acc, 0, 0, 0);
            }
            float h0 = lrelu(acc[0]), h1 = lrelu(acc[1]);
            float h2 = lrelu(acc[2]), h3 = lrelu(acc[3]);
            ps_lo += h0 + h1;  pq_lo = fmaf(h0, h0, fmaf(h1, h1, pq_lo));
            ps_hi += h2 + h3;  pq_hi = fmaf(h2, h2, fmaf(h3, h3, pq_hi));
            char* wp = (char*)hbb + bofs(ay + 2, 2 * col + dxl + 2) + sub * 8;
            *(uint2*)wp = make_uint2(pk2(h0, h1), pk2(h2, h3));
        }

        // GN stats reduce: over anchors (xor 1,2,4,8) then dx halves (xor 32)
        #pragma unroll
        for (int m = 1; m <= 8; m <<= 1) {
            ps_lo += __shfl_xor(ps_lo, m); ps_hi += __shfl_xor(ps_hi, m);
            pq_lo += __shfl_xor(pq_lo, m); pq_hi += __shfl_xor(pq_hi, m);
        }
        ps_lo += __shfl_xor(ps_lo, 32); ps_hi += __shfl_xor(ps_hi, 32);
        pq_lo += __shfl_xor(pq_lo, 32); pq_hi += __shfl_xor(pq_hi, 32);
        if (lane == 0)  { red[wid * 8 + 0] = ps_lo; red[wid * 8 + 1] = ps_hi;
                          red[wid * 8 + 4] = pq_lo; red[wid * 8 + 5] = pq_hi; }
        if (lane == 16) { red[wid * 8 + 2] = ps_lo; red[wid * 8 + 6] = pq_lo; }
        __syncthreads();                               // B1

        // ---- fold GN into conv2 operands ----
        float scv[6], shv[6];
        #pragma unroll
        for (int g3 = 0; g3 < 3; ++g3) {
            float s = 0.f, q = 0.f;
            #pragma unroll
            for (int w = 0; w < 8; ++w) { s += red[w * 8 + g3]; q += red[w * 8 + 4 + g3]; }
            float mean = s * (1.f / 2048.f);
            float var  = q * (1.f / 2048.f) - mean * mean;
            float inv  = rsqrtf(var + 1e-5f);
            #pragma unroll
            for (int k = 0; k < 2; ++k) {
                int c = 2 * g3 + k;
                scv[c] = inv * gv[c];
                shv[c] = bv[c] - mean * scv[c];
            }
        }
        float bias2q[4];
        #pragma unroll
        for (int r = 0; r < 4; ++r) {
            float b = b2q[r];
            #pragma unroll
            for (int ch = 0; ch < 6; ++ch) b = fmaf(s2q[r * 6 + ch], shv[ch], b);
            bias2q[r] = b;
        }
        const f32x4 ai2 = {bias2q[0], bias2q[1], bias2q[2], bias2q[3]};
        unsigned sp0 = pk2(scv[0], scv[1]), sp1 = pk2(scv[2], scv[3]), sp2 = pk2(scv[4], scv[5]);
        uint4 w2s[8];
        #pragma unroll
        for (int c = 0; c < 8; ++c) {
            w2s[c].x = hmul2(cw2[c].x, sp0);
            w2s[c].y = hmul2(cw2[c].y, sp1);
            w2s[c].z = hmul2(cw2[c].z, sp2);
            w2s[c].w = 0u;
        }
        // h pads <- -sh/sc
        float ph[6];
        #pragma unroll
        for (int c = 0; c < 6; ++c) {
            float rs = (fabsf(scv[c]) > 1e-20f) ? 1.f / scv[c] : 0.f;
            ph[c] = -shv[c] * rs;
        }
        uint4 padq = make_uint4(pk2(ph[0], ph[1]), pk2(ph[2], ph[3]), pk2(ph[4], ph[5]), 0u);
        if (tid < 272) {
            int row, cc;
            if (tid < 72)       { row = tid / 36;             cc = tid % 36; }
            else if (tid < 144) { row = 34 + (tid - 72) / 36; cc = (tid - 72) % 36; }
            else {
                int q4 = tid - 144;
                row = 2 + (q4 >> 2);
                int c4 = q4 & 3;
                cc = (c4 < 2) ? c4 : c4 + 32;
            }
            *(uint4*)((char*)hbb + bofs(row, cc)) = padq;
        }
        __syncthreads();                               // B2

        // ================= conv2 (folded GN, bias in acc-init) =================
        for (int g8 = 0; g8 < 4; ++g8) {
            const int ay = (wid << 2) + g8;
            const int ab = ay * 576;
            f32x4 acc = ai2;
            #pragma unroll
            for (int c = 0; c < 8; ++c) {
                half8 pv = *(const half8*)(hb + ab + toff[c]);
                acc = __builtin_amdgcn_mfma_f32_16x16x32_f16(
                        __builtin_bit_cast(half8, w2s[c]), pv, acc, 0, 0, 0);
            }
            char* zp = (char*)zxb + bofs(ay + 2, 2 * col + dxl + 2);
            if (sub == 0) {       // z0..z3: b64 RMW
                uint2 zo = *(uint2*)zp;
                float2 za = up2(zo.x), zc = up2(zo.y);
                float z0 = 0.5f * za.x + 0.5f * lrelu(acc[0]);
                float z1 = 0.5f * za.y + 0.5f * lrelu(acc[1]);
                float z2 = 0.5f * zc.x + 0.5f * lrelu(acc[2]);
                float z3 = 0.5f * zc.y + 0.5f * lrelu(acc[3]);
                *(uint2*)zp = make_uint2(pk2(z0, z1), pk2(z2, z3));
            } else {              // z4: u16 RMW (keeps img0 in hi half)
                _Float16* pz = (_Float16*)(zp + 8);
                float z4 = 0.5f * (float)pz[0] + 0.5f * lrelu(acc[0]);
                pz[0] = (_Float16)z4;
            }
        }
        __syncthreads();                               // B3
    }

    // ================= head: out[o] = <z, wh[o]> + bh[o] =================
    if (tid < 256) {
        const int yy = tid >> 3, xx0 = (tid & 7) << 2;
        float zf[5][4];
        #pragma unroll
        for (int i = 0; i < 4; ++i) {
            const unsigned* bp = (const unsigned*)((const char*)zxb + bofs(yy + 2, xx0 + 2 + i));
            float2 f0 = up2(bp[0]), f1 = up2(bp[1]), f2 = up2(bp[2]);
            zf[0][i] = f0.x; zf[1][i] = f0.y; zf[2][i] = f1.x; zf[3][i] = f1.y; zf[4][i] = f2.x;
        }
        float ho[10];
        #pragma unroll
        for (int o = 0; o < 10; ++o) ho[o] = 0.f;
        #pragma unroll
        for (int c = 0; c < 5; ++c) {
            #pragma unroll
            for (int o = 0; o < 10; ++o) {
                float4 wv = *(const float4*)&wh[(o * 5 + c) * 1024 + yy * 32 + xx0];
                ho[o] = fmaf(zf[c][0], wv.x, ho[o]);
                ho[o] = fmaf(zf[c][1], wv.y, ho[o]);
                ho[o] = fmaf(zf[c][2], wv.z, ho[o]);
                ho[o] = fmaf(zf[c][3], wv.w, ho[o]);
            }
        }
        #pragma unroll
        for (int m = 1; m < 64; m <<= 1) {
            #pragma unroll
            for (int o = 0; o < 10; ++o) ho[o] += __shfl_xor(ho[o], m);
        }
        if (lane == 0) {
            #pragma unroll
            for (int o = 0; o < 10; ++o) red[wid * 10 + o] = ho[o];
        }
    }
    __syncthreads();
    if (tid < 10)
        out[n * 10 + tid] = red[tid] + red[10 + tid] + red[20 + tid] + red[30 + tid] + bh[tid];
}

extern "C" void kernel_launch(void* const* d_in, const int* in_sizes, int n_in,
                              void* d_out, int out_size, void* d_ws, size_t ws_size,
                              hipStream_t stream) {
    const float* image = (const float*)d_in[0];
    const float* w1    = (const float*)d_in[1];
    const float* b1    = (const float*)d_in[2];
    const float* gam   = (const float*)d_in[3];
    const float* bet   = (const float*)d_in[4];
    const float* w2    = (const float*)d_in[5];
    const float* b2    = (const float*)d_in[6];
    const float* wh    = (const float*)d_in[7];
    const float* bh    = (const float*)d_in[8];
    float* out = (float*)d_out;
    unsigned* ws = (unsigned*)d_ws;

    pack_weights<<<5, 256, 0, stream>>>(w1, w2, ws);

    const int N = in_sizes[0] / (3 * 32 * 32);   // 1024 images
    deq_kernel<<<N, 512, 0, stream>>>(image, ws, b1, gam, bet, b2, wh, bh, out);
}

// Round 7
// 604.382 us; speedup vs baseline: 1.8853x; 1.8853x over previous
//
#include <hip/hip_runtime.h>
#include <hip/hip_fp16.h>

// DEQ classifier, dx-packed MFMA version (spill-fixed).
// One block per image (1024 x 512 threads, 8 waves). LDS: two planes of
// 8-channel f16 pixel bundles (16 B) on a 36x36 zero-padded grid, with
// bundle-address swizzle  bofs(y,x) = ((y*36+x)*16) ^ ((x&8)<<1).
//   zxb: [z0..z4, img0..2]    hbb: [h0..h5, 0, 0]
// Conv as MFMA 16x16x32:
//   A[16 rows=(dx*8+oc)][32 k] : weights, prepacked in d_ws (kx = tx-dx)
//   B[32 k][16 cols=anchor a]  : pixel bundle at (ay+ty, 2a+tx), 1 b128/lane
//   k = (tap = ty*6+tx over 5x6 window, ch); 8 chunks of 4 taps.
//   D: col=lane&15=anchor, row=(lane>>4)*4+reg = dx*8+oc
// GroupNorm folded into conv2 (w2*sc inline per chunk, h-pads=-sh/sc, bias fold).
// Register budget: <=128 VGPR (launch_bounds(512,4) -> 2 blocks/CU):
//   - no w2s[8] materialization (chunk-outer loop, wsc live 1 chunk)
//   - no s2q[24] (S2 table read from LDS at fold time)

typedef _Float16 half8 __attribute__((ext_vector_type(8)));
typedef float f32x4 __attribute__((ext_vector_type(4)));

__device__ __forceinline__ unsigned pk2(float a, float b) {
    __half2 h = __float22half2_rn(make_float2(a, b));
    return *reinterpret_cast<unsigned*>(&h);
}
__device__ __forceinline__ float2 up2(unsigned u) {
    __half2 h = *reinterpret_cast<__half2*>(&u);
    return __half22float2(h);
}
__device__ __forceinline__ unsigned hmul2(unsigned a, unsigned b) {
    __half2 r = __hmul2(*reinterpret_cast<__half2*>(&a), *reinterpret_cast<__half2*>(&b));
    return *reinterpret_cast<unsigned*>(&r);
}
__device__ __forceinline__ float lrelu(float x) { return fmaxf(x, 0.01f * x); }
__device__ __forceinline__ int bofs(int y, int x) {
    return ((y * 36 + x) * 16) ^ ((x & 8) << 1);
}

// ---- prep: dx-packed A-fragments + tap-sum table ----
// ws[0..2047]    : conv1 A-frags, 8 chunks x 64 lanes x 4 dw
//   lane l: row = l&15 (dx=row>>3, oc=row&7), tap = 4c + (l>>4); elem j = ch j
//   value = w1[oc][ch][ty][tx-dx] (ty=tap/6, tx=tap%6), 0 if OOB/oc>=6/tap>=30
// ws[2048..4095] : conv2 A-frags from w2 (0 if oc>=5, ch>=6)
// ws[4096..4125] : S2[oc][ch] = sum_tap w2[oc][ch][tap]  (f32)
__global__ void pack_weights(const float* __restrict__ w1,
                             const float* __restrict__ w2,
                             unsigned* __restrict__ ws)
{
    int t = blockIdx.x * 256 + threadIdx.x;
    if (t < 512) {
        int c = t >> 6, l = t & 63;
        int row = l & 15, tgw = l >> 4;
        int dx = row >> 3, oc = row & 7, tap = 4 * c + tgw;
        unsigned q[4];
        #pragma unroll
        for (int d = 0; d < 4; ++d) {
            float v0 = 0.f, v1 = 0.f;
            if (oc < 6 && tap < 30) {
                int ty = tap / 6, kx = tap % 6 - dx;
                if (kx >= 0 && kx < 5) {
                    v0 = w1[(oc * 8 + 2 * d) * 25 + ty * 5 + kx];
                    v1 = w1[(oc * 8 + 2 * d + 1) * 25 + ty * 5 + kx];
                }
            }
            q[d] = pk2(v0, v1);
        }
        *(uint4*)&ws[t * 4] = make_uint4(q[0], q[1], q[2], q[3]);
    } else if (t < 1024) {
        int u = t - 512;
        int c = u >> 6, l = u & 63;
        int row = l & 15, tgw = l >> 4;
        int dx = row >> 3, oc = row & 7, tap = 4 * c + tgw;
        unsigned q[4];
        #pragma unroll
        for (int d = 0; d < 4; ++d) {
            float v0 = 0.f, v1 = 0.f;
            if (oc < 5 && tap < 30) {
                int ty = tap / 6, kx = tap % 6 - dx;
                if (kx >= 0 && kx < 5) {
                    if (2 * d < 6)     v0 = w2[(oc * 6 + 2 * d) * 25 + ty * 5 + kx];
                    if (2 * d + 1 < 6) v1 = w2[(oc * 6 + 2 * d + 1) * 25 + ty * 5 + kx];
                }
            }
            q[d] = pk2(v0, v1);
        }
        *(uint4*)&ws[2048 + u * 4] = make_uint4(q[0], q[1], q[2], q[3]);
    } else if (t < 1054) {
        int idx = t - 1024;
        int oc = idx / 6, ch = idx % 6;
        float s = 0.f;
        for (int tap = 0; tap < 25; ++tap) s += w2[(oc * 6 + ch) * 25 + tap];
        ((float*)ws)[4096 + idx] = s;
    }
}

__global__ __launch_bounds__(512, 4)
void deq_kernel(const float* __restrict__ image,
                const unsigned* __restrict__ wks,
                const float* __restrict__ b1,
                const float* __restrict__ gam, const float* __restrict__ bet,
                const float* __restrict__ b2,
                const float* __restrict__ wh, const float* __restrict__ bh,
                float* __restrict__ out)
{
    __shared__ __align__(16) unsigned zxb[36 * 36 * 4];
    __shared__ __align__(16) unsigned hbb[36 * 36 * 4];
    __shared__ float red[64];
    __shared__ float s2s[32];

    const int n    = blockIdx.x;
    const int tid  = threadIdx.x;
    const int lane = tid & 63;
    const int wid  = tid >> 6;          // 0..7
    const int col  = lane & 15;         // anchor: pixels 2col, 2col+1
    const int tg   = lane >> 4;
    const int dxl  = tg >> 1;           // this lane's output dx
    const int sub  = tg & 1;            // 0: ch0-3, 1: ch4-7

    for (int p = tid; p < 36 * 36 * 4; p += 512) { zxb[p] = 0u; hbb[p] = 0u; }
    if (tid < 30) s2s[tid] = ((const float*)wks)[4096 + tid];
    __syncthreads();

    if (tid < 256) {    // image -> bundle ch 5..7
        const int yy = tid >> 3, xx0 = (tid & 7) << 2;
        float4 i0 = *(const float4*)&image[(n * 3 + 0) * 1024 + yy * 32 + xx0];
        float4 i1 = *(const float4*)&image[(n * 3 + 1) * 1024 + yy * 32 + xx0];
        float4 i2 = *(const float4*)&image[(n * 3 + 2) * 1024 + yy * 32 + xx0];
        float a0[4] = {i0.x, i0.y, i0.z, i0.w};
        float a1[4] = {i1.x, i1.y, i1.z, i1.w};
        float a2[4] = {i2.x, i2.y, i2.z, i2.w};
        #pragma unroll
        for (int i = 0; i < 4; ++i) {
            unsigned* bp = (unsigned*)((char*)zxb + bofs(yy + 2, xx0 + 2 + i));
            bp[2] = pk2(0.f, a0[i]);
            bp[3] = pk2(a1[i], a2[i]);
        }
    }

    // weight A-fragments (persistent: 64 VGPR)
    uint4 cw1[8], cw2[8];
    #pragma unroll
    for (int c = 0; c < 8; ++c) {
        cw1[c] = *(const uint4*)&wks[(c * 64 + lane) * 4];
        cw2[c] = *(const uint4*)&wks[2048 + (c * 64 + lane) * 4];
    }
    // per-lane per-chunk B-read byte offsets
    int toff[8];
    #pragma unroll
    for (int c = 0; c < 8; ++c) {
        int t = 4 * c + tg;
        int ty = 0, tx = 0;
        if (t < 30) { ty = t / 6; tx = t % 6; }
        int xr = 2 * col + tx;
        toff[c] = ty * 576 + ((xr * 16) ^ ((xr & 8) << 1));
    }

    float b1q[4], b2q[4];
    #pragma unroll
    for (int r = 0; r < 4; ++r) {
        int oc = (tg * 4 + r) & 7;
        b1q[r] = (oc < 6) ? b1[oc] : 0.f;
        b2q[r] = (oc < 5) ? b2[oc] : 0.f;
    }
    const f32x4 ai1 = {b1q[0], b1q[1], b1q[2], b1q[3]};

    __syncthreads();

    const char* zb = (const char*)zxb;
    const char* hb = (const char*)hbb;
    const int ay0 = wid << 2;

    #pragma unroll 1
    for (int it = 0; it < 30; ++it) {
        // ================= conv1 (chunk-outer, acc[4] row-groups) =================
        f32x4 acc[4];
        #pragma unroll
        for (int g8 = 0; g8 < 4; ++g8) acc[g8] = ai1;
        #pragma unroll
        for (int c = 0; c < 8; ++c) {
            half8 wf = __builtin_bit_cast(half8, cw1[c]);
            #pragma unroll
            for (int g8 = 0; g8 < 4; ++g8) {
                half8 pv = *(const half8*)(zb + (ay0 + g8) * 576 + toff[c]);
                acc[g8] = __builtin_amdgcn_mfma_f32_16x16x32_f16(wf, pv, acc[g8], 0, 0, 0);
            }
        }
        float ps_lo = 0.f, ps_hi = 0.f, pq_lo = 0.f, pq_hi = 0.f;
        #pragma unroll
        for (int g8 = 0; g8 < 4; ++g8) {
            float h0 = lrelu(acc[g8][0]), h1 = lrelu(acc[g8][1]);
            float h2 = lrelu(acc[g8][2]), h3 = lrelu(acc[g8][3]);
            ps_lo += h0 + h1;  pq_lo = fmaf(h0, h0, fmaf(h1, h1, pq_lo));
            ps_hi += h2 + h3;  pq_hi = fmaf(h2, h2, fmaf(h3, h3, pq_hi));
            char* wp = (char*)hbb + bofs(ay0 + g8 + 2, 2 * col + dxl + 2) + sub * 8;
            *(uint2*)wp = make_uint2(pk2(h0, h1), pk2(h2, h3));
        }

        // GN stats reduce: anchors (xor 1..8) then dx halves (xor 32)
        #pragma unroll
        for (int m = 1; m <= 8; m <<= 1) {
            ps_lo += __shfl_xor(ps_lo, m); ps_hi += __shfl_xor(ps_hi, m);
            pq_lo += __shfl_xor(pq_lo, m); pq_hi += __shfl_xor(pq_hi, m);
        }
        ps_lo += __shfl_xor(ps_lo, 32); ps_hi += __shfl_xor(ps_hi, 32);
        pq_lo += __shfl_xor(pq_lo, 32); pq_hi += __shfl_xor(pq_hi, 32);
        if (lane == 0)  { red[wid * 8 + 0] = ps_lo; red[wid * 8 + 1] = ps_hi;
                          red[wid * 8 + 4] = pq_lo; red[wid * 8 + 5] = pq_hi; }
        if (lane == 16) { red[wid * 8 + 2] = ps_lo; red[wid * 8 + 6] = pq_lo; }
        __syncthreads();                               // B1

        // ---- fold GN into conv2 operands ----
        float scv[6], shv[6];
        #pragma unroll
        for (int g3 = 0; g3 < 3; ++g3) {
            float s = 0.f, q = 0.f;
            #pragma unroll
            for (int w = 0; w < 8; ++w) { s += red[w * 8 + g3]; q += red[w * 8 + 4 + g3]; }
            float mean = s * (1.f / 2048.f);
            float var  = q * (1.f / 2048.f) - mean * mean;
            float inv  = rsqrtf(var + 1e-5f);
            #pragma unroll
            for (int k = 0; k < 2; ++k) {
                int c = 2 * g3 + k;
                scv[c] = inv * gam[c];
                shv[c] = bet[c] - mean * scv[c];
            }
        }
        f32x4 ai2;
        #pragma unroll
        for (int r = 0; r < 4; ++r) {
            int ocr = (tg * 4 + r) & 7;
            int base = (ocr < 5) ? ocr * 6 : 0;
            float db = 0.f;
            #pragma unroll
            for (int ch = 0; ch < 6; ++ch) db = fmaf(s2s[base + ch], shv[ch], db);
            ai2[r] = b2q[r] + ((ocr < 5) ? db : 0.f);
        }
        unsigned sp0 = pk2(scv[0], scv[1]), sp1 = pk2(scv[2], scv[3]), sp2 = pk2(scv[4], scv[5]);
        // h pads <- -sh/sc
        {
            float ph[6];
            #pragma unroll
            for (int c = 0; c < 6; ++c) {
                float rs = (fabsf(scv[c]) > 1e-20f) ? 1.f / scv[c] : 0.f;
                ph[c] = -shv[c] * rs;
            }
            uint4 padq = make_uint4(pk2(ph[0], ph[1]), pk2(ph[2], ph[3]), pk2(ph[4], ph[5]), 0u);
            if (tid < 272) {
                int row, cc;
                if (tid < 72)       { row = tid / 36;             cc = tid % 36; }
                else if (tid < 144) { row = 34 + (tid - 72) / 36; cc = (tid - 72) % 36; }
                else {
                    int q4 = tid - 144;
                    row = 2 + (q4 >> 2);
                    int c4 = q4 & 3;
                    cc = (c4 < 2) ? c4 : c4 + 32;
                }
                *(uint4*)((char*)hbb + bofs(row, cc)) = padq;
            }
        }
        __syncthreads();                               // B2

        // ============ conv2 (chunk-outer; scale w2 inline, 1-chunk live) ============
        #pragma unroll
        for (int g8 = 0; g8 < 4; ++g8) acc[g8] = ai2;
        #pragma unroll
        for (int c = 0; c < 8; ++c) {
            uint4 wsc;
            wsc.x = hmul2(cw2[c].x, sp0);
            wsc.y = hmul2(cw2[c].y, sp1);
            wsc.z = hmul2(cw2[c].z, sp2);
            wsc.w = 0u;
            half8 wf = __builtin_bit_cast(half8, wsc);
            #pragma unroll
            for (int g8 = 0; g8 < 4; ++g8) {
                half8 pv = *(const half8*)(hb + (ay0 + g8) * 576 + toff[c]);
                acc[g8] = __builtin_amdgcn_mfma_f32_16x16x32_f16(wf, pv, acc[g8], 0, 0, 0);
            }
        }
        #pragma unroll
        for (int g8 = 0; g8 < 4; ++g8) {
            char* zp = (char*)zxb + bofs(ay0 + g8 + 2, 2 * col + dxl + 2);
            if (sub == 0) {       // z0..z3: b64 RMW
                uint2 zo = *(uint2*)zp;
                float2 za = up2(zo.x), zc = up2(zo.y);
                float z0 = 0.5f * za.x + 0.5f * lrelu(acc[g8][0]);
                float z1 = 0.5f * za.y + 0.5f * lrelu(acc[g8][1]);
                float z2 = 0.5f * zc.x + 0.5f * lrelu(acc[g8][2]);
                float z3 = 0.5f * zc.y + 0.5f * lrelu(acc[g8][3]);
                *(uint2*)zp = make_uint2(pk2(z0, z1), pk2(z2, z3));
            } else {              // z4: u16 RMW (keeps img0 in hi half)
                _Float16* pz = (_Float16*)(zp + 8);
                float z4 = 0.5f * (float)pz[0] + 0.5f * lrelu(acc[g8][0]);
                pz[0] = (_Float16)z4;
            }
        }
        __syncthreads();                               // B3
    }

    // ================= head: out[o] = <z, wh[o]> + bh[o] =================
    if (tid < 256) {
        const int yy = tid >> 3, xx0 = (tid & 7) << 2;
        float zf[5][4];
        #pragma unroll
        for (int i = 0; i < 4; ++i) {
            const unsigned* bp = (const unsigned*)((const char*)zxb + bofs(yy + 2, xx0 + 2 + i));
            float2 f0 = up2(bp[0]), f1 = up2(bp[1]), f2 = up2(bp[2]);
            zf[0][i] = f0.x; zf[1][i] = f0.y; zf[2][i] = f1.x; zf[3][i] = f1.y; zf[4][i] = f2.x;
        }
        float ho[10];
        #pragma unroll
        for (int o = 0; o < 10; ++o) ho[o] = 0.f;
        #pragma unroll
        for (int c = 0; c < 5; ++c) {
            #pragma unroll
            for (int o = 0; o < 10; ++o) {
                float4 wv = *(const float4*)&wh[(o * 5 + c) * 1024 + yy * 32 + xx0];
                ho[o] = fmaf(zf[c][0], wv.x, ho[o]);
                ho[o] = fmaf(zf[c][1], wv.y, ho[o]);
                ho[o] = fmaf(zf[c][2], wv.z, ho[o]);
                ho[o] = fmaf(zf[c][3], wv.w, ho[o]);
            }
        }
        #pragma unroll
        for (int m = 1; m < 64; m <<= 1) {
            #pragma unroll
            for (int o = 0; o < 10; ++o) ho[o] += __shfl_xor(ho[o], m);
        }
        if (lane == 0) {
            #pragma unroll
            for (int o = 0; o < 10; ++o) red[wid * 10 + o] = ho[o];
        }
    }
    __syncthreads();
    if (tid < 10)
        out[n * 10 + tid] = red[tid] + red[10 + tid] + red[20 + tid] + red[30 + tid] + bh[tid];
}

extern "C" void kernel_launch(void* const* d_in, const int* in_sizes, int n_in,
                              void* d_out, int out_size, void* d_ws, size_t ws_size,
                              hipStream_t stream) {
    const float* image = (const float*)d_in[0];
    const float* w1    = (const float*)d_in[1];
    const float* b1    = (const float*)d_in[2];
    const float* gam   = (const float*)d_in[3];
    const float* bet   = (const float*)d_in[4];
    const float* w2    = (const float*)d_in[5];
    const float* b2    = (const float*)d_in[6];
    const float* wh    = (const float*)d_in[7];
    const float* bh    = (const float*)d_in[8];
    float* out = (float*)d_out;
    unsigned* ws = (unsigned*)d_ws;

    pack_weights<<<5, 256, 0, stream>>>(w1, w2, ws);

    const int N = in_sizes[0] / (3 * 32 * 32);   // 1024 images
    deq_kernel<<<N, 512, 0, stream>>>(image, ws, b1, gam, bet, b2, wh, bh, out);
}

// Round 8
// 544.555 us; speedup vs baseline: 2.0924x; 1.1099x over previous
//
#include <hip/hip_runtime.h>
#include <hip/hip_fp16.h>

// DEQ classifier, dx-packed MFMA version, weights-in-LDS (spill-free).
// One block per image (1024 x 512 threads, 8 waves). LDS: two planes of
// 8-channel f16 pixel bundles (16 B) on a 36x36 zero-padded grid, with
// bundle-address swizzle  bofs(y,x) = ((y*36+x)*16) ^ ((x&8)<<1).
//   zxb: [z0..z4, img0..2]    hbb: [h0..h5, 0, 0]
// Conv as MFMA 16x16x32:
//   A[16 rows=(dx*8+oc)][32 k] : weight frags, staged in LDS (ds_read per chunk)
//   B[32 k][16 cols=anchor a]  : pixel bundle at (ay+ty, 2a+tx), 1 b128/lane
//   k = (tap = ty*6+tx over 5x6 window, ch); 8 chunks of 4 taps.
//   D: col=lane&15=anchor, row=(lane>>4)*4+reg = dx*8+oc
// GroupNorm folded into conv2 (w2*sc inline per chunk, h-pads=-sh/sc, bias fold).
// Register budget: launch_bounds(512,2) -> observed backend cap 256/2=128;
// no persistent weight regs -> ~80-100 VGPR, no scratch spills.

typedef _Float16 half8 __attribute__((ext_vector_type(8)));
typedef float f32x4 __attribute__((ext_vector_type(4)));

__device__ __forceinline__ unsigned pk2(float a, float b) {
    __half2 h = __float22half2_rn(make_float2(a, b));
    return *reinterpret_cast<unsigned*>(&h);
}
__device__ __forceinline__ float2 up2(unsigned u) {
    __half2 h = *reinterpret_cast<__half2*>(&u);
    return __half22float2(h);
}
__device__ __forceinline__ unsigned hmul2(unsigned a, unsigned b) {
    __half2 r = __hmul2(*reinterpret_cast<__half2*>(&a), *reinterpret_cast<__half2*>(&b));
    return *reinterpret_cast<unsigned*>(&r);
}
__device__ __forceinline__ float lrelu(float x) { return fmaxf(x, 0.01f * x); }
__device__ __forceinline__ int bofs(int y, int x) {
    return ((y * 36 + x) * 16) ^ ((x & 8) << 1);
}

// ---- prep: dx-packed A-fragments + tap-sum table ----
// ws[0..2047]    : conv1 A-frags, 8 chunks x 64 lanes x 4 dw
//   lane l: row = l&15 (dx=row>>3, oc=row&7), tap = 4c + (l>>4); elem j = ch j
//   value = w1[oc][ch][ty][tx-dx] (ty=tap/6, tx=tap%6), 0 if OOB/oc>=6/tap>=30
// ws[2048..4095] : conv2 A-frags from w2 (0 if oc>=5, ch>=6)
// ws[4096..4125] : S2[oc][ch] = sum_tap w2[oc][ch][tap]  (f32)
__global__ void pack_weights(const float* __restrict__ w1,
                             const float* __restrict__ w2,
                             unsigned* __restrict__ ws)
{
    int t = blockIdx.x * 256 + threadIdx.x;
    if (t < 512) {
        int c = t >> 6, l = t & 63;
        int row = l & 15, tgw = l >> 4;
        int dx = row >> 3, oc = row & 7, tap = 4 * c + tgw;
        unsigned q[4];
        #pragma unroll
        for (int d = 0; d < 4; ++d) {
            float v0 = 0.f, v1 = 0.f;
            if (oc < 6 && tap < 30) {
                int ty = tap / 6, kx = tap % 6 - dx;
                if (kx >= 0 && kx < 5) {
                    v0 = w1[(oc * 8 + 2 * d) * 25 + ty * 5 + kx];
                    v1 = w1[(oc * 8 + 2 * d + 1) * 25 + ty * 5 + kx];
                }
            }
            q[d] = pk2(v0, v1);
        }
        *(uint4*)&ws[t * 4] = make_uint4(q[0], q[1], q[2], q[3]);
    } else if (t < 1024) {
        int u = t - 512;
        int c = u >> 6, l = u & 63;
        int row = l & 15, tgw = l >> 4;
        int dx = row >> 3, oc = row & 7, tap = 4 * c + tgw;
        unsigned q[4];
        #pragma unroll
        for (int d = 0; d < 4; ++d) {
            float v0 = 0.f, v1 = 0.f;
            if (oc < 5 && tap < 30) {
                int ty = tap / 6, kx = tap % 6 - dx;
                if (kx >= 0 && kx < 5) {
                    if (2 * d < 6)     v0 = w2[(oc * 6 + 2 * d) * 25 + ty * 5 + kx];
                    if (2 * d + 1 < 6) v1 = w2[(oc * 6 + 2 * d + 1) * 25 + ty * 5 + kx];
                }
            }
            q[d] = pk2(v0, v1);
        }
        *(uint4*)&ws[2048 + u * 4] = make_uint4(q[0], q[1], q[2], q[3]);
    } else if (t < 1054) {
        int idx = t - 1024;
        int oc = idx / 6, ch = idx % 6;
        float s = 0.f;
        for (int tap = 0; tap < 25; ++tap) s += w2[(oc * 6 + ch) * 25 + tap];
        ((float*)ws)[4096 + idx] = s;
    }
}

__global__ __launch_bounds__(512, 2)
void deq_kernel(const float* __restrict__ image,
                const unsigned* __restrict__ wks,
                const float* __restrict__ b1,
                const float* __restrict__ gam, const float* __restrict__ bet,
                const float* __restrict__ b2,
                const float* __restrict__ wh, const float* __restrict__ bh,
                float* __restrict__ out)
{
    __shared__ __align__(16) unsigned zxb[36 * 36 * 4];
    __shared__ __align__(16) unsigned hbb[36 * 36 * 4];
    __shared__ __align__(16) unsigned wl1[2048];   // conv1 A-frags (8 KB)
    __shared__ __align__(16) unsigned wl2[2048];   // conv2 A-frags (8 KB)
    __shared__ float red[64];
    __shared__ float s2s[32];

    const int n    = blockIdx.x;
    const int tid  = threadIdx.x;
    const int lane = tid & 63;
    const int wid  = tid >> 6;          // 0..7
    const int col  = lane & 15;         // anchor: pixels 2col, 2col+1
    const int tg   = lane >> 4;
    const int dxl  = tg >> 1;           // this lane's output dx
    const int sub  = tg & 1;            // 0: ch0-3, 1: ch4-7

    for (int p = tid; p < 36 * 36 * 4; p += 512) { zxb[p] = 0u; hbb[p] = 0u; }
    // stage weight fragment tables into LDS
    for (int p = tid; p < 2048; p += 512) { wl1[p] = wks[p]; wl2[p] = wks[2048 + p]; }
    if (tid < 30) s2s[tid] = ((const float*)wks)[4096 + tid];
    __syncthreads();

    if (tid < 256) {    // image -> bundle ch 5..7
        const int yy = tid >> 3, xx0 = (tid & 7) << 2;
        float4 i0 = *(const float4*)&image[(n * 3 + 0) * 1024 + yy * 32 + xx0];
        float4 i1 = *(const float4*)&image[(n * 3 + 1) * 1024 + yy * 32 + xx0];
        float4 i2 = *(const float4*)&image[(n * 3 + 2) * 1024 + yy * 32 + xx0];
        float a0[4] = {i0.x, i0.y, i0.z, i0.w};
        float a1[4] = {i1.x, i1.y, i1.z, i1.w};
        float a2[4] = {i2.x, i2.y, i2.z, i2.w};
        #pragma unroll
        for (int i = 0; i < 4; ++i) {
            unsigned* bp = (unsigned*)((char*)zxb + bofs(yy + 2, xx0 + 2 + i));
            bp[2] = pk2(0.f, a0[i]);
            bp[3] = pk2(a1[i], a2[i]);
        }
    }

    // per-lane per-chunk B-read byte offsets
    int toff[8];
    #pragma unroll
    for (int c = 0; c < 8; ++c) {
        int t = 4 * c + tg;
        int ty = 0, tx = 0;
        if (t < 30) { ty = t / 6; tx = t % 6; }
        int xr = 2 * col + tx;
        toff[c] = ty * 576 + ((xr * 16) ^ ((xr & 8) << 1));
    }

    float b1q[4], b2q[4];
    #pragma unroll
    for (int r = 0; r < 4; ++r) {
        int oc = (tg * 4 + r) & 7;
        b1q[r] = (oc < 6) ? b1[oc] : 0.f;
        b2q[r] = (oc < 5) ? b2[oc] : 0.f;
    }
    const f32x4 ai1 = {b1q[0], b1q[1], b1q[2], b1q[3]};

    __syncthreads();

    const char* zb = (const char*)zxb;
    const char* hb = (const char*)hbb;
    const int ay0 = wid << 2;
    const int wlo = lane * 4;           // this lane's fragment dword base

    #pragma unroll 1
    for (int it = 0; it < 30; ++it) {
        // ================= conv1 (chunk-outer, acc[4] row-groups) =================
        f32x4 acc[4];
        #pragma unroll
        for (int g8 = 0; g8 < 4; ++g8) acc[g8] = ai1;
        #pragma unroll
        for (int c = 0; c < 8; ++c) {
            half8 wf = *(const half8*)&wl1[c * 256 + wlo];
            #pragma unroll
            for (int g8 = 0; g8 < 4; ++g8) {
                half8 pv = *(const half8*)(zb + (ay0 + g8) * 576 + toff[c]);
                acc[g8] = __builtin_amdgcn_mfma_f32_16x16x32_f16(wf, pv, acc[g8], 0, 0, 0);
            }
        }
        float ps_lo = 0.f, ps_hi = 0.f, pq_lo = 0.f, pq_hi = 0.f;
        #pragma unroll
        for (int g8 = 0; g8 < 4; ++g8) {
            float h0 = lrelu(acc[g8][0]), h1 = lrelu(acc[g8][1]);
            float h2 = lrelu(acc[g8][2]), h3 = lrelu(acc[g8][3]);
            ps_lo += h0 + h1;  pq_lo = fmaf(h0, h0, fmaf(h1, h1, pq_lo));
            ps_hi += h2 + h3;  pq_hi = fmaf(h2, h2, fmaf(h3, h3, pq_hi));
            char* wp = (char*)hbb + bofs(ay0 + g8 + 2, 2 * col + dxl + 2) + sub * 8;
            *(uint2*)wp = make_uint2(pk2(h0, h1), pk2(h2, h3));
        }

        // GN stats reduce: anchors (xor 1..8) then dx halves (xor 32)
        #pragma unroll
        for (int m = 1; m <= 8; m <<= 1) {
            ps_lo += __shfl_xor(ps_lo, m); ps_hi += __shfl_xor(ps_hi, m);
            pq_lo += __shfl_xor(pq_lo, m); pq_hi += __shfl_xor(pq_hi, m);
        }
        ps_lo += __shfl_xor(ps_lo, 32); ps_hi += __shfl_xor(ps_hi, 32);
        pq_lo += __shfl_xor(pq_lo, 32); pq_hi += __shfl_xor(pq_hi, 32);
        if (lane == 0)  { red[wid * 8 + 0] = ps_lo; red[wid * 8 + 1] = ps_hi;
                          red[wid * 8 + 4] = pq_lo; red[wid * 8 + 5] = pq_hi; }
        if (lane == 16) { red[wid * 8 + 2] = ps_lo; red[wid * 8 + 6] = pq_lo; }
        __syncthreads();                               // B1

        // ---- fold GN into conv2 operands ----
        float scv[6], shv[6];
        #pragma unroll
        for (int g3 = 0; g3 < 3; ++g3) {
            float s = 0.f, q = 0.f;
            #pragma unroll
            for (int w = 0; w < 8; ++w) { s += red[w * 8 + g3]; q += red[w * 8 + 4 + g3]; }
            float mean = s * (1.f / 2048.f);
            float var  = q * (1.f / 2048.f) - mean * mean;
            float inv  = rsqrtf(var + 1e-5f);
            #pragma unroll
            for (int k = 0; k < 2; ++k) {
                int c = 2 * g3 + k;
                scv[c] = inv * gam[c];
                shv[c] = bet[c] - mean * scv[c];
            }
        }
        f32x4 ai2;
        #pragma unroll
        for (int r = 0; r < 4; ++r) {
            int ocr = (tg * 4 + r) & 7;
            int base = (ocr < 5) ? ocr * 6 : 0;
            float db = 0.f;
            #pragma unroll
            for (int ch = 0; ch < 6; ++ch) db = fmaf(s2s[base + ch], shv[ch], db);
            ai2[r] = b2q[r] + ((ocr < 5) ? db : 0.f);
        }
        unsigned sp0 = pk2(scv[0], scv[1]), sp1 = pk2(scv[2], scv[3]), sp2 = pk2(scv[4], scv[5]);
        // h pads <- -sh/sc
        {
            float ph[6];
            #pragma unroll
            for (int c = 0; c < 6; ++c) {
                float rs = (fabsf(scv[c]) > 1e-20f) ? 1.f / scv[c] : 0.f;
                ph[c] = -shv[c] * rs;
            }
            uint4 padq = make_uint4(pk2(ph[0], ph[1]), pk2(ph[2], ph[3]), pk2(ph[4], ph[5]), 0u);
            if (tid < 272) {
                int row, cc;
                if (tid < 72)       { row = tid / 36;             cc = tid % 36; }
                else if (tid < 144) { row = 34 + (tid - 72) / 36; cc = (tid - 72) % 36; }
                else {
                    int q4 = tid - 144;
                    row = 2 + (q4 >> 2);
                    int c4 = q4 & 3;
                    cc = (c4 < 2) ? c4 : c4 + 32;
                }
                *(uint4*)((char*)hbb + bofs(row, cc)) = padq;
            }
        }
        __syncthreads();                               // B2

        // ============ conv2 (chunk-outer; LDS frag + inline scale) ============
        #pragma unroll
        for (int g8 = 0; g8 < 4; ++g8) acc[g8] = ai2;
        #pragma unroll
        for (int c = 0; c < 8; ++c) {
            uint4 wr = *(const uint4*)&wl2[c * 256 + wlo];
            uint4 wsc;
            wsc.x = hmul2(wr.x, sp0);
            wsc.y = hmul2(wr.y, sp1);
            wsc.z = hmul2(wr.z, sp2);
            wsc.w = 0u;
            half8 wf = __builtin_bit_cast(half8, wsc);
            #pragma unroll
            for (int g8 = 0; g8 < 4; ++g8) {
                half8 pv = *(const half8*)(hb + (ay0 + g8) * 576 + toff[c]);
                acc[g8] = __builtin_amdgcn_mfma_f32_16x16x32_f16(wf, pv, acc[g8], 0, 0, 0);
            }
        }
        #pragma unroll
        for (int g8 = 0; g8 < 4; ++g8) {
            char* zp = (char*)zxb + bofs(ay0 + g8 + 2, 2 * col + dxl + 2);
            if (sub == 0) {       // z0..z3: b64 RMW
                uint2 zo = *(uint2*)zp;
                float2 za = up2(zo.x), zc = up2(zo.y);
                float z0 = 0.5f * za.x + 0.5f * lrelu(acc[g8][0]);
                float z1 = 0.5f * za.y + 0.5f * lrelu(acc[g8][1]);
                float z2 = 0.5f * zc.x + 0.5f * lrelu(acc[g8][2]);
                float z3 = 0.5f * zc.y + 0.5f * lrelu(acc[g8][3]);
                *(uint2*)zp = make_uint2(pk2(z0, z1), pk2(z2, z3));
            } else {              // z4: u16 RMW (keeps img0 in hi half)
                _Float16* pz = (_Float16*)(zp + 8);
                float z4 = 0.5f * (float)pz[0] + 0.5f * lrelu(acc[g8][0]);
                pz[0] = (_Float16)z4;
            }
        }
        __syncthreads();                               // B3
    }

    // ================= head: out[o] = <z, wh[o]> + bh[o] =================
    if (tid < 256) {
        const int yy = tid >> 3, xx0 = (tid & 7) << 2;
        float zf[5][4];
        #pragma unroll
        for (int i = 0; i < 4; ++i) {
            const unsigned* bp = (const unsigned*)((const char*)zxb + bofs(yy + 2, xx0 + 2 + i));
            float2 f0 = up2(bp[0]), f1 = up2(bp[1]), f2 = up2(bp[2]);
            zf[0][i] = f0.x; zf[1][i] = f0.y; zf[2][i] = f1.x; zf[3][i] = f1.y; zf[4][i] = f2.x;
        }
        float ho[10];
        #pragma unroll
        for (int o = 0; o < 10; ++o) ho[o] = 0.f;
        #pragma unroll
        for (int c = 0; c < 5; ++c) {
            #pragma unroll
            for (int o = 0; o < 10; ++o) {
                float4 wv = *(const float4*)&wh[(o * 5 + c) * 1024 + yy * 32 + xx0];
                ho[o] = fmaf(zf[c][0], wv.x, ho[o]);
                ho[o] = fmaf(zf[c][1], wv.y, ho[o]);
                ho[o] = fmaf(zf[c][2], wv.z, ho[o]);
                ho[o] = fmaf(zf[c][3], wv.w, ho[o]);
            }
        }
        #pragma unroll
        for (int m = 1; m < 64; m <<= 1) {
            #pragma unroll
            for (int o = 0; o < 10; ++o) ho[o] += __shfl_xor(ho[o], m);
        }
        if (lane == 0) {
            #pragma unroll
            for (int o = 0; o < 10; ++o) red[wid * 10 + o] = ho[o];
        }
    }
    __syncthreads();
    if (tid < 10)
        out[n * 10 + tid] = red[tid] + red[10 + tid] + red[20 + tid] + red[30 + tid] + bh[tid];
}

extern "C" void kernel_launch(void* const* d_in, const int* in_sizes, int n_in,
                              void* d_out, int out_size, void* d_ws, size_t ws_size,
                              hipStream_t stream) {
    const float* image = (const float*)d_in[0];
    const float* w1    = (const float*)d_in[1];
    const float* b1    = (const float*)d_in[2];
    const float* gam   = (const float*)d_in[3];
    const float* bet   = (const float*)d_in[4];
    const float* w2    = (const float*)d_in[5];
    const float* b2    = (const float*)d_in[6];
    const float* wh    = (const float*)d_in[7];
    const float* bh    = (const float*)d_in[8];
    float* out = (float*)d_out;
    unsigned* ws = (unsigned*)d_ws;

    pack_weights<<<5, 256, 0, stream>>>(w1, w2, ws);

    const int N = in_sizes[0] / (3 * 32 * 32);   // 1024 images
    deq_kernel<<<N, 512, 0, stream>>>(image, ws, b1, gam, bet, b2, wh, bh, out);
}

// Round 9
// 356.273 us; speedup vs baseline: 3.1982x; 1.5285x over previous
//
#include <hip/hip_runtime.h>
#include <hip/hip_fp16.h>

// DEQ classifier, dx-packed MFMA, 256-thread blocks, weights-in-registers.
// One block per image (1024 x 256 threads, 4 waves; wave owns 8 y-rows as
// two 4-row passes). LDS: two planes of 8-channel f16 pixel bundles (16 B)
// on a 36x36 zero-padded grid, bundle swizzle bofs(y,x)=((y*36+x)*16)^((x&8)<<1).
//   zxb: [z0..z4, img0..2]    hbb: [h0..h5, 0, 0]
// Conv as MFMA 16x16x32:
//   A[16 rows=(dx*8+oc)][32 k] : weight frags in VGPRs (cw1/cw2, 64 regs)
//   B[32 k][16 cols=anchor a]  : pixel bundle at (ay+ty, 2a+tx), 1 b128/lane
//   k = (tap = ty*6+tx over 5x6 window, ch); 8 chunks of 4 taps.
//   D: col=lane&15=anchor, row=(lane>>4)*4+reg = dx*8+oc
// GroupNorm folded into conv2 (w2*sc inline per chunk, h-pads=-sh/sc, bias fold).
// Register budget: launch_bounds(256,2) -> backend cap 256/2=128 (observed
// rule cap=256/waves_per_eu); est. live ~114 -> no scratch spills.

typedef _Float16 half8 __attribute__((ext_vector_type(8)));
typedef float f32x4 __attribute__((ext_vector_type(4)));

__device__ __forceinline__ unsigned pk2(float a, float b) {
    __half2 h = __float22half2_rn(make_float2(a, b));
    return *reinterpret_cast<unsigned*>(&h);
}
__device__ __forceinline__ float2 up2(unsigned u) {
    __half2 h = *reinterpret_cast<__half2*>(&u);
    return __half22float2(h);
}
__device__ __forceinline__ unsigned hmul2(unsigned a, unsigned b) {
    __half2 r = __hmul2(*reinterpret_cast<__half2*>(&a), *reinterpret_cast<__half2*>(&b));
    return *reinterpret_cast<unsigned*>(&r);
}
__device__ __forceinline__ float lrelu(float x) { return fmaxf(x, 0.01f * x); }
__device__ __forceinline__ int bofs(int y, int x) {
    return ((y * 36 + x) * 16) ^ ((x & 8) << 1);
}

// ---- prep: dx-packed A-fragments + tap-sum table ----
// ws[0..2047]    : conv1 A-frags, 8 chunks x 64 lanes x 4 dw
//   lane l: row = l&15 (dx=row>>3, oc=row&7), tap = 4c + (l>>4); elem j = ch j
//   value = w1[oc][ch][ty][tx-dx] (ty=tap/6, tx=tap%6), 0 if OOB/oc>=6/tap>=30
// ws[2048..4095] : conv2 A-frags from w2 (0 if oc>=5, ch>=6)
// ws[4096..4125] : S2[oc][ch] = sum_tap w2[oc][ch][tap]  (f32)
__global__ void pack_weights(const float* __restrict__ w1,
                             const float* __restrict__ w2,
                             unsigned* __restrict__ ws)
{
    int t = blockIdx.x * 256 + threadIdx.x;
    if (t < 512) {
        int c = t >> 6, l = t & 63;
        int row = l & 15, tgw = l >> 4;
        int dx = row >> 3, oc = row & 7, tap = 4 * c + tgw;
        unsigned q[4];
        #pragma unroll
        for (int d = 0; d < 4; ++d) {
            float v0 = 0.f, v1 = 0.f;
            if (oc < 6 && tap < 30) {
                int ty = tap / 6, kx = tap % 6 - dx;
                if (kx >= 0 && kx < 5) {
                    v0 = w1[(oc * 8 + 2 * d) * 25 + ty * 5 + kx];
                    v1 = w1[(oc * 8 + 2 * d + 1) * 25 + ty * 5 + kx];
                }
            }
            q[d] = pk2(v0, v1);
        }
        *(uint4*)&ws[t * 4] = make_uint4(q[0], q[1], q[2], q[3]);
    } else if (t < 1024) {
        int u = t - 512;
        int c = u >> 6, l = u & 63;
        int row = l & 15, tgw = l >> 4;
        int dx = row >> 3, oc = row & 7, tap = 4 * c + tgw;
        unsigned q[4];
        #pragma unroll
        for (int d = 0; d < 4; ++d) {
            float v0 = 0.f, v1 = 0.f;
            if (oc < 5 && tap < 30) {
                int ty = tap / 6, kx = tap % 6 - dx;
                if (kx >= 0 && kx < 5) {
                    if (2 * d < 6)     v0 = w2[(oc * 6 + 2 * d) * 25 + ty * 5 + kx];
                    if (2 * d + 1 < 6) v1 = w2[(oc * 6 + 2 * d + 1) * 25 + ty * 5 + kx];
                }
            }
            q[d] = pk2(v0, v1);
        }
        *(uint4*)&ws[2048 + u * 4] = make_uint4(q[0], q[1], q[2], q[3]);
    } else if (t < 1054) {
        int idx = t - 1024;
        int oc = idx / 6, ch = idx % 6;
        float s = 0.f;
        for (int tap = 0; tap < 25; ++tap) s += w2[(oc * 6 + ch) * 25 + tap];
        ((float*)ws)[4096 + idx] = s;
    }
}

__global__ __launch_bounds__(256, 2)
void deq_kernel(const float* __restrict__ image,
                const unsigned* __restrict__ wks,
                const float* __restrict__ b1,
                const float* __restrict__ gam, const float* __restrict__ bet,
                const float* __restrict__ b2,
                const float* __restrict__ wh, const float* __restrict__ bh,
                float* __restrict__ out)
{
    __shared__ __align__(16) unsigned zxb[36 * 36 * 4];
    __shared__ __align__(16) unsigned hbb[36 * 36 * 4];
    __shared__ float red[48];
    __shared__ float s2s[32];

    const int n    = blockIdx.x;
    const int tid  = threadIdx.x;
    const int lane = tid & 63;
    const int wid  = tid >> 6;          // 0..3
    const int col  = lane & 15;         // anchor: pixels 2col, 2col+1
    const int tg   = lane >> 4;
    const int dxl  = tg >> 1;           // this lane's output dx
    const int sub  = tg & 1;            // 0: ch0-3, 1: ch4-7

    for (int p = tid; p < 36 * 36 * 4; p += 256) { zxb[p] = 0u; hbb[p] = 0u; }
    if (tid < 30) s2s[tid] = ((const float*)wks)[4096 + tid];
    __syncthreads();

    {   // image -> bundle ch 5..7 (all 256 threads: one 1x4 strip each)
        const int yy = tid >> 3, xx0 = (tid & 7) << 2;
        float4 i0 = *(const float4*)&image[(n * 3 + 0) * 1024 + yy * 32 + xx0];
        float4 i1 = *(const float4*)&image[(n * 3 + 1) * 1024 + yy * 32 + xx0];
        float4 i2 = *(const float4*)&image[(n * 3 + 2) * 1024 + yy * 32 + xx0];
        float a0[4] = {i0.x, i0.y, i0.z, i0.w};
        float a1[4] = {i1.x, i1.y, i1.z, i1.w};
        float a2[4] = {i2.x, i2.y, i2.z, i2.w};
        #pragma unroll
        for (int i = 0; i < 4; ++i) {
            unsigned* bp = (unsigned*)((char*)zxb + bofs(yy + 2, xx0 + 2 + i));
            bp[2] = pk2(0.f, a0[i]);
            bp[3] = pk2(a1[i], a2[i]);
        }
    }

    // weight A-fragments in registers (64 VGPR, reused all 30 iters)
    uint4 cw1[8], cw2[8];
    #pragma unroll
    for (int c = 0; c < 8; ++c) {
        cw1[c] = *(const uint4*)&wks[(c * 64 + lane) * 4];
        cw2[c] = *(const uint4*)&wks[2048 + (c * 64 + lane) * 4];
    }
    // per-lane per-chunk B-read byte offsets
    int toff[8];
    #pragma unroll
    for (int c = 0; c < 8; ++c) {
        int t = 4 * c + tg;
        int ty = 0, tx = 0;
        if (t < 30) { ty = t / 6; tx = t % 6; }
        int xr = 2 * col + tx;
        toff[c] = ty * 576 + ((xr * 16) ^ ((xr & 8) << 1));
    }

    float b1q[4], b2q[4];
    #pragma unroll
    for (int r = 0; r < 4; ++r) {
        int oc = (tg * 4 + r) & 7;
        b1q[r] = (oc < 6) ? b1[oc] : 0.f;
        b2q[r] = (oc < 5) ? b2[oc] : 0.f;
    }
    const f32x4 ai1 = {b1q[0], b1q[1], b1q[2], b1q[3]};

    __syncthreads();

    const char* zb = (const char*)zxb;
    const char* hb = (const char*)hbb;
    const int ay0 = wid << 3;           // wave owns rows ay0..ay0+7

    #pragma unroll 1
    for (int it = 0; it < 30; ++it) {
        // ================= conv1 (two 4-row passes, chunk-outer) =================
        float ps_lo = 0.f, ps_hi = 0.f, pq_lo = 0.f, pq_hi = 0.f;
        #pragma unroll
        for (int half = 0; half < 2; ++half) {
            const int ayh = ay0 + half * 4;
            f32x4 acc[4];
            #pragma unroll
            for (int g = 0; g < 4; ++g) acc[g] = ai1;
            #pragma unroll
            for (int c = 0; c < 8; ++c) {
                half8 wf = __builtin_bit_cast(half8, cw1[c]);
                #pragma unroll
                for (int g = 0; g < 4; ++g) {
                    half8 pv = *(const half8*)(zb + (ayh + g) * 576 + toff[c]);
                    acc[g] = __builtin_amdgcn_mfma_f32_16x16x32_f16(wf, pv, acc[g], 0, 0, 0);
                }
            }
            #pragma unroll
            for (int g = 0; g < 4; ++g) {
                float h0 = lrelu(acc[g][0]), h1 = lrelu(acc[g][1]);
                float h2 = lrelu(acc[g][2]), h3 = lrelu(acc[g][3]);
                ps_lo += h0 + h1;  pq_lo = fmaf(h0, h0, fmaf(h1, h1, pq_lo));
                ps_hi += h2 + h3;  pq_hi = fmaf(h2, h2, fmaf(h3, h3, pq_hi));
                char* wp = (char*)hbb + bofs(ayh + g + 2, 2 * col + dxl + 2) + sub * 8;
                *(uint2*)wp = make_uint2(pk2(h0, h1), pk2(h2, h3));
            }
        }

        // GN stats reduce: anchors (xor 1..8) then dx halves (xor 32)
        #pragma unroll
        for (int m = 1; m <= 8; m <<= 1) {
            ps_lo += __shfl_xor(ps_lo, m); ps_hi += __shfl_xor(ps_hi, m);
            pq_lo += __shfl_xor(pq_lo, m); pq_hi += __shfl_xor(pq_hi, m);
        }
        ps_lo += __shfl_xor(ps_lo, 32); ps_hi += __shfl_xor(ps_hi, 32);
        pq_lo += __shfl_xor(pq_lo, 32); pq_hi += __shfl_xor(pq_hi, 32);
        if (lane == 0)  { red[wid * 8 + 0] = ps_lo; red[wid * 8 + 1] = ps_hi;
                          red[wid * 8 + 4] = pq_lo; red[wid * 8 + 5] = pq_hi; }
        if (lane == 16) { red[wid * 8 + 2] = ps_lo; red[wid * 8 + 6] = pq_lo; }
        __syncthreads();                               // B1

        // ---- fold GN into conv2 operands ----
        float scv[6], shv[6];
        #pragma unroll
        for (int g3 = 0; g3 < 3; ++g3) {
            float s = 0.f, q = 0.f;
            #pragma unroll
            for (int w = 0; w < 4; ++w) { s += red[w * 8 + g3]; q += red[w * 8 + 4 + g3]; }
            float mean = s * (1.f / 2048.f);
            float var  = q * (1.f / 2048.f) - mean * mean;
            float inv  = rsqrtf(var + 1e-5f);
            #pragma unroll
            for (int k = 0; k < 2; ++k) {
                int c = 2 * g3 + k;
                scv[c] = inv * gam[c];
                shv[c] = bet[c] - mean * scv[c];
            }
        }
        f32x4 ai2;
        #pragma unroll
        for (int r = 0; r < 4; ++r) {
            int ocr = (tg * 4 + r) & 7;
            int base = (ocr < 5) ? ocr * 6 : 0;
            float db = 0.f;
            #pragma unroll
            for (int ch = 0; ch < 6; ++ch) db = fmaf(s2s[base + ch], shv[ch], db);
            ai2[r] = b2q[r] + ((ocr < 5) ? db : 0.f);
        }
        unsigned sp0 = pk2(scv[0], scv[1]), sp1 = pk2(scv[2], scv[3]), sp2 = pk2(scv[4], scv[5]);
        // h pads <- -sh/sc
        {
            float ph[6];
            #pragma unroll
            for (int c = 0; c < 6; ++c) {
                float rs = (fabsf(scv[c]) > 1e-20f) ? 1.f / scv[c] : 0.f;
                ph[c] = -shv[c] * rs;
            }
            uint4 padq = make_uint4(pk2(ph[0], ph[1]), pk2(ph[2], ph[3]), pk2(ph[4], ph[5]), 0u);
            for (int t = tid; t < 272; t += 256) {
                int row, cc;
                if (t < 72)       { row = t / 36;             cc = t % 36; }
                else if (t < 144) { row = 34 + (t - 72) / 36; cc = (t - 72) % 36; }
                else {
                    int q4 = t - 144;
                    row = 2 + (q4 >> 2);
                    int c4 = q4 & 3;
                    cc = (c4 < 2) ? c4 : c4 + 32;
                }
                *(uint4*)((char*)hbb + bofs(row, cc)) = padq;
            }
        }
        __syncthreads();                               // B2

        // ============ conv2 (two 4-row passes; scale w2 inline per chunk) ============
        #pragma unroll
        for (int half = 0; half < 2; ++half) {
            const int ayh = ay0 + half * 4;
            f32x4 acc[4];
            #pragma unroll
            for (int g = 0; g < 4; ++g) acc[g] = ai2;
            #pragma unroll
            for (int c = 0; c < 8; ++c) {
                uint4 wsc;
                wsc.x = hmul2(cw2[c].x, sp0);
                wsc.y = hmul2(cw2[c].y, sp1);
                wsc.z = hmul2(cw2[c].z, sp2);
                wsc.w = 0u;
                half8 wf = __builtin_bit_cast(half8, wsc);
                #pragma unroll
                for (int g = 0; g < 4; ++g) {
                    half8 pv = *(const half8*)(hb + (ayh + g) * 576 + toff[c]);
                    acc[g] = __builtin_amdgcn_mfma_f32_16x16x32_f16(wf, pv, acc[g], 0, 0, 0);
                }
            }
            #pragma unroll
            for (int g = 0; g < 4; ++g) {
                char* zp = (char*)zxb + bofs(ayh + g + 2, 2 * col + dxl + 2);
                if (sub == 0) {       // z0..z3: b64 RMW
                    uint2 zo = *(uint2*)zp;
                    float2 za = up2(zo.x), zc = up2(zo.y);
                    float z0 = 0.5f * za.x + 0.5f * lrelu(acc[g][0]);
                    float z1 = 0.5f * za.y + 0.5f * lrelu(acc[g][1]);
                    float z2 = 0.5f * zc.x + 0.5f * lrelu(acc[g][2]);
                    float z3 = 0.5f * zc.y + 0.5f * lrelu(acc[g][3]);
                    *(uint2*)zp = make_uint2(pk2(z0, z1), pk2(z2, z3));
                } else {              // z4: u16 RMW (keeps img0 in hi half)
                    _Float16* pz = (_Float16*)(zp + 8);
                    float z4 = 0.5f * (float)pz[0] + 0.5f * lrelu(acc[g][0]);
                    pz[0] = (_Float16)z4;
                }
            }
        }
        __syncthreads();                               // B3
    }

    // ================= head: out[o] = <z, wh[o]> + bh[o] =================
    {
        const int yy = tid >> 3, xx0 = (tid & 7) << 2;
        float zf[5][4];
        #pragma unroll
        for (int i = 0; i < 4; ++i) {
            const unsigned* bp = (const unsigned*)((const char*)zxb + bofs(yy + 2, xx0 + 2 + i));
            float2 f0 = up2(bp[0]), f1 = up2(bp[1]), f2 = up2(bp[2]);
            zf[0][i] = f0.x; zf[1][i] = f0.y; zf[2][i] = f1.x; zf[3][i] = f1.y; zf[4][i] = f2.x;
        }
        float ho[10];
        #pragma unroll
        for (int o = 0; o < 10; ++o) ho[o] = 0.f;
        #pragma unroll
        for (int c = 0; c < 5; ++c) {
            #pragma unroll
            for (int o = 0; o < 10; ++o) {
                float4 wv = *(const float4*)&wh[(o * 5 + c) * 1024 + yy * 32 + xx0];
                ho[o] = fmaf(zf[c][0], wv.x, ho[o]);
                ho[o] = fmaf(zf[c][1], wv.y, ho[o]);
                ho[o] = fmaf(zf[c][2], wv.z, ho[o]);
                ho[o] = fmaf(zf[c][3], wv.w, ho[o]);
            }
        }
        #pragma unroll
        for (int m = 1; m < 64; m <<= 1) {
            #pragma unroll
            for (int o = 0; o < 10; ++o) ho[o] += __shfl_xor(ho[o], m);
        }
        if (lane == 0) {
            #pragma unroll
            for (int o = 0; o < 10; ++o) red[wid * 10 + o] = ho[o];
        }
    }
    __syncthreads();
    if (tid < 10)
        out[n * 10 + tid] = red[tid] + red[10 + tid] + red[20 + tid] + red[30 + tid] + bh[tid];
}

extern "C" void kernel_launch(void* const* d_in, const int* in_sizes, int n_in,
                              void* d_out, int out_size, void* d_ws, size_t ws_size,
                              hipStream_t stream) {
    const float* image = (const float*)d_in[0];
    const float* w1    = (const float*)d_in[1];
    const float* b1    = (const float*)d_in[2];
    const float* gam   = (const float*)d_in[3];
    const float* bet   = (const float*)d_in[4];
    const float* w2    = (const float*)d_in[5];
    const float* b2    = (const float*)d_in[6];
    const float* wh    = (const float*)d_in[7];
    const float* bh    = (const float*)d_in[8];
    float* out = (float*)d_out;
    unsigned* ws = (unsigned*)d_ws;

    pack_weights<<<5, 256, 0, stream>>>(w1, w2, ws);

    const int N = in_sizes[0] / (3 * 32 * 32);   // 1024 images
    deq_kernel<<<N, 256, 0, stream>>>(image, ws, b1, gam, bet, b2, wh, bh, out);
}